// Round 5
// baseline (200.354 us; speedup 1.0000x reference)
//
#include <hip/hip_runtime.h>

#define DEV __device__ __forceinline__

typedef unsigned short u16;
typedef __attribute__((ext_vector_type(8))) __bf16 bf16x8;
typedef __attribute__((ext_vector_type(4))) float f32x4;
typedef __attribute__((ext_vector_type(8))) unsigned short u16x8;
typedef __attribute__((ext_vector_type(4))) unsigned short u16x4;

// Problem constants: B=16, T=4096, Din=Dout=S=256
static constexpr int NB = 16;
static constexpr int NT = 4096;
static constexpr int NCH = 64;   // chunks per batch (L = 64)
static constexpr int LCH = 64;

DEV u16 f2bf(float f) {
  unsigned u = __builtin_bit_cast(unsigned, f);
  u += 0x7fffu + ((u >> 16) & 1u);
  return (u16)(u >> 16);
}
DEV float bf2f(u16 h) {
  unsigned u = ((unsigned)h) << 16;
  return __builtin_bit_cast(float, u);
}

DEV void gl_lds16(const void* gp, void* lp) {
  __builtin_amdgcn_global_load_lds(
      (__attribute__((address_space(1))) void*)(void*)gp,
      (__attribute__((address_space(3))) void*)lp, 16, 0, 0);
}

DEV bf16x8 cvt8(float4 a, float4 b) {
  u16x8 o;
  o[0] = f2bf(a.x); o[1] = f2bf(a.y); o[2] = f2bf(a.z); o[3] = f2bf(a.w);
  o[4] = f2bf(b.x); o[5] = f2bf(b.y); o[6] = f2bf(b.z); o[7] = f2bf(b.w);
  return __builtin_bit_cast(bf16x8, o);
}

// ---------------- prep: a = tanh(a_raw); wq = [b;d] bf16; c -> bf16 ----------------
__global__ __launch_bounds__(256) void prep_k(const float* __restrict__ a_raw,
                                              const float* __restrict__ b,
                                              const float* __restrict__ c,
                                              const float* __restrict__ d,
                                              float* __restrict__ af,
                                              u16* __restrict__ wq,
                                              u16* __restrict__ cw) {
  int i = blockIdx.x * 256 + threadIdx.x;  // grid 256 -> i < 65536
  if (i < 256) af[i] = tanhf(a_raw[i]);
  wq[i] = f2bf(b[i]);
  wq[65536 + i] = f2bf(d[i]);
  cw[i] = f2bf(c[i]);
}

// ---------------- gemm1 v3: barrier-free direct-fragment GEMM --------------------
// [Bu | Ud] = u @ [b;d]^T + per-chunk scan carries. NO LDS, NO barriers.
// grid 4096: bx>>2 = chunk (64 rows), bx&3 = 128-col panel (0,1->bu; 2,3->ud).
// 256 thr = 4 waves, wave tile 64x32 (mi=4, ni=2). A fragments loaded straight
// from u in MFMA layout (lane l: row mi*16+(l&15), k (l>>4)*8) and converted
// in-register; B fragments are single dwordx4 from L2-resident wq. Waves are
// fully independent -> latency hidden by ILP + 12 waves/CU, no barrier drain.
__global__ __launch_bounds__(256, 3) void gemm1_k(const float* __restrict__ u,
                                                  const u16* __restrict__ wq,
                                                  const float* __restrict__ af,
                                                  u16* __restrict__ bu,
                                                  u16* __restrict__ ud,
                                                  float* __restrict__ carry) {
  const int tid = threadIdx.x;
  const int lane = tid & 63;
  const int wid = tid >> 6;           // 0..3 col group within panel
  const int bx = blockIdx.x;
  const int chunk = bx >> 2;
  const int panel = bx & 3;
  const size_t row0 = (size_t)chunk * 64;

  const int lr = lane & 15;           // fragment row/col within 16
  const int lk = (lane >> 4) * 8;     // fragment k offset

  const f32x4 zero = {0.f, 0.f, 0.f, 0.f};
  f32x4 acc[4][2];
#pragma unroll
  for (int i = 0; i < 4; ++i) { acc[i][0] = zero; acc[i][1] = zero; }

  const float* ubase = u + (row0 + lr) * 256 + lk;
  const u16* wbase = wq + (size_t)(panel * 128 + wid * 32 + lr) * 256 + lk;

#pragma unroll
  for (int kt = 0; kt < 4; ++kt) {
#pragma unroll
    for (int ks = 0; ks < 2; ++ks) {
      const int k = kt * 64 + ks * 32;
      // A fragments: 4 mi x (2 float4)
      float4 a0[4], a1[4];
#pragma unroll
      for (int mi = 0; mi < 4; ++mi) {
        const float* p = ubase + (size_t)mi * 16 * 256 + k;
        a0[mi] = *reinterpret_cast<const float4*>(p);
        a1[mi] = *reinterpret_cast<const float4*>(p + 4);
      }
      // B fragments: 2 ni x dwordx4
      bf16x8 bf[2];
#pragma unroll
      for (int ni = 0; ni < 2; ++ni)
        bf[ni] = *reinterpret_cast<const bf16x8*>(wbase + (size_t)ni * 16 * 256 + k);
      bf16x8 afr[4];
#pragma unroll
      for (int mi = 0; mi < 4; ++mi) afr[mi] = cvt8(a0[mi], a1[mi]);
#pragma unroll
      for (int mi = 0; mi < 4; ++mi)
#pragma unroll
        for (int ni = 0; ni < 2; ++ni)
          acc[mi][ni] = __builtin_amdgcn_mfma_f32_16x16x32_bf16(
              afr[mi], bf[ni], acc[mi][ni], 0, 0, 0);
    }
  }

  // ---- write outputs. C/D layout: col = lane&15, row = (lane>>4)*4 + q ----
#pragma unroll
  for (int mi = 0; mi < 4; ++mi) {
    int rl = mi * 16 + (lane >> 4) * 4;
#pragma unroll
    for (int ni = 0; ni < 2; ++ni) {
      int col = panel * 128 + wid * 32 + ni * 16 + lr;
#pragma unroll
      for (int q = 0; q < 4; ++q) {
        size_t R = row0 + rl + q;
        u16 h = f2bf(acc[mi][ni][q]);
        if (panel < 2)
          bu[R * 256 + (((col >> 3) ^ ((int)R & 7)) * 8) + (col & 7)] = h;
        else
          ud[R * 256 + (col - 256)] = h;
      }
    }
  }

  // ---- chunk carry: carry[chunk][s] = sum_t a_s^(63-t) Bu[t][s] ----
  if (panel < 2) {
    const int tb = (lane >> 4) * 4;  // lane-group timestep base within frag
#pragma unroll
    for (int ni = 0; ni < 2; ++ni) {
      int col = panel * 128 + wid * 32 + ni * 16 + lr;
      float a = af[col];
      float c2 = a * a, c4 = c2 * c2, c8 = c4 * c4;
      float a12 = c8 * c4;
      float a13 = a12 * a;
      float base = (tb == 0) ? a12 : (tb == 4) ? c8 : (tb == 8) ? c4 : 1.0f;
      float p = base, s = 0.f;
#pragma unroll
      for (int mi = 3; mi >= 0; --mi) {
#pragma unroll
        for (int q = 3; q >= 0; --q) {
          s = fmaf(p, acc[mi][ni][q], s);
          if (q) p *= a;
        }
        if (mi) p *= a13;  // exponent +13: from (mi,q=0) to (mi-1,q=3)
      }
      s += __shfl_xor(s, 16, 64);
      s += __shfl_xor(s, 32, 64);
      if ((lane >> 4) == 0) carry[(size_t)chunk * 256 + col] = s;
    }
  }
}

// ---------------- scan2: exclusive scan of carries over 64 chunks ----------------
__global__ __launch_bounds__(256) void scan2_k(const float* __restrict__ carry,
                                               const float* __restrict__ af,
                                               float* __restrict__ initb) {
  int b = blockIdx.x;  // 16
  int s = threadIdx.x;
  float a = af[s];
  float aL = a;
#pragma unroll
  for (int i = 0; i < 6; ++i) aL *= aL;  // a^64
  float x = 0.f;
  for (int k = 0; k < NCH; ++k) {
    size_t idx = ((size_t)(b * NCH + k)) * 256 + s;
    float cv = carry[idx];
    initb[idx] = x;
    x = fmaf(aL, x, cv);
  }
}

// ---------------- gemm2: y = xs@c^T + Ud, with in-LDS xs reconstruction --------
// grid (512, 2): bx = row tile (= chunk pair), by = col half. 512 thr, 8 waves 2x4,
// wave tile 64x32. LDS: XS [128][256] bf16 swizzled (64KB) + CS [128][64] (16KB).
__global__ __launch_bounds__(512, 4) void gemm2_k(const u16* __restrict__ bu,
                                                  const u16* __restrict__ cw,
                                                  const u16* __restrict__ ud,
                                                  const float* __restrict__ af,
                                                  const float* __restrict__ initb,
                                                  float* __restrict__ y) {
  __shared__ u16 XS[128 * 256];
  __shared__ u16 CS[128 * 64];
  const int tid = threadIdx.x;
  const int lane = tid & 63;
  const int wid = tid >> 6;
  const int wr = wid >> 2, wc = wid & 3;
  const int bx = blockIdx.x;          // rows bx*128..+128 ; chunks 2bx, 2bx+1
  const int col0 = blockIdx.y * 128;

  // stage bu tile (linear copy; data pre-swizzled in global)
  const char* src = (const char*)bu + (size_t)bx * 65536;
#pragma unroll
  for (int j = 0; j < 8; ++j)
    gl_lds16(src + j * 8192 + tid * 16, (char*)XS + j * 8192 + wid * 1024);
  // stage C step 0
#pragma unroll
  for (int r = 0; r < 2; ++r) {
    int brow = r * 64 + (tid >> 3);
    int sc = (tid & 7) ^ (brow & 7);
    gl_lds16(cw + (size_t)(col0 + brow) * 256 + 0 + sc * 8,
             (char*)CS + r * 8192 + wid * 1024);
  }
  __syncthreads();

  // ---- recon xs in place: 2 chunk halves x 256 states ----
  {
    const int hf = tid >> 8;        // 0/1
    const int s = tid & 255;
    const float a = af[s];
    float x = initb[(size_t)(bx * 2 + hf) * 256 + s];
    const int r0 = hf * 64;
    const int slot = s >> 3;
    const int off = (s & 7);
#pragma unroll 8
    for (int t = 0; t < 64; ++t) {
      int r = r0 + t;
      int bi = r * 256 + ((slot ^ (r & 7)) * 8) + off;
      x = fmaf(a, x, bf2f(XS[bi]));
      XS[bi] = f2bf(x);
    }
  }

  // ---- init acc from ud (global, overlaps recon of other waves) ----
  f32x4 acc[4][2];
#pragma unroll
  for (int mi = 0; mi < 4; ++mi) {
    int rlb = wr * 64 + mi * 16 + (lane >> 4) * 4;
#pragma unroll
    for (int ni = 0; ni < 2; ++ni) {
      int col = col0 + wc * 32 + ni * 16 + (lane & 15);
#pragma unroll
      for (int q = 0; q < 4; ++q)
        acc[mi][ni][q] = bf2f(ud[(size_t)(bx * 128 + rlb + q) * 256 + col]);
    }
  }
  __syncthreads();

  // ---- K loop over c (K=256, 4 steps) ----
#pragma unroll
  for (int kt = 0; kt < 4; ++kt) {
#pragma unroll
    for (int kk = 0; kk < 2; ++kk) {
      const int ksl = kk * 4 + (lane >> 4);       // local slot in CS
      const int ksg = kt * 8 + ksl;               // global slot in XS
      bf16x8 afr[4], bfr[2];
#pragma unroll
      for (int mi = 0; mi < 4; ++mi) {
        int ar = wr * 64 + mi * 16 + (lane & 15);
        afr[mi] = *reinterpret_cast<const bf16x8*>(&XS[ar * 256 + ((ksg ^ (ar & 7)) * 8)]);
      }
#pragma unroll
      for (int ni = 0; ni < 2; ++ni) {
        int nr = wc * 32 + ni * 16 + (lane & 15);
        bfr[ni] = *reinterpret_cast<const bf16x8*>(&CS[nr * 64 + ((ksl ^ (nr & 7)) * 8)]);
      }
#pragma unroll
      for (int mi = 0; mi < 4; ++mi)
#pragma unroll
        for (int ni = 0; ni < 2; ++ni)
          acc[mi][ni] = __builtin_amdgcn_mfma_f32_16x16x32_bf16(
              afr[mi], bfr[ni], acc[mi][ni], 0, 0, 0);
    }
    if (kt < 3) {
      __syncthreads();  // readers done with CS
#pragma unroll
      for (int r = 0; r < 2; ++r) {
        int brow = r * 64 + (tid >> 3);
        int sc = (tid & 7) ^ (brow & 7);
        gl_lds16(cw + (size_t)(col0 + brow) * 256 + (kt + 1) * 64 + sc * 8,
                 (char*)CS + r * 8192 + wid * 1024);
      }
      __syncthreads();  // staged (vmcnt drained)
    }
  }

  // ---- epilogue: y fp32 ----
#pragma unroll
  for (int mi = 0; mi < 4; ++mi) {
    int rlb = wr * 64 + mi * 16 + (lane >> 4) * 4;
#pragma unroll
    for (int ni = 0; ni < 2; ++ni) {
      int col = col0 + wc * 32 + ni * 16 + (lane & 15);
#pragma unroll
      for (int q = 0; q < 4; ++q)
        y[(size_t)(bx * 128 + rlb + q) * 256 + col] = acc[mi][ni][q];
    }
  }
}

extern "C" void kernel_launch(void* const* d_in, const int* in_sizes, int n_in,
                              void* d_out, int out_size, void* d_ws, size_t ws_size,
                              hipStream_t stream) {
  const float* u = (const float*)d_in[0];
  const float* a_raw = (const float*)d_in[1];
  const float* b = (const float*)d_in[2];
  const float* c = (const float*)d_in[3];
  const float* d = (const float*)d_in[4];
  float* y = (float*)d_out;
  char* ws = (char*)d_ws;

  const size_t MB = 1u << 20;
  float* af = (float*)(ws);                       // 1 KB
  u16* wq = (u16*)(ws + 65536);                   // 256 KB  [b;d] stacked
  u16* cw = (u16*)(ws + 65536 + 262144);          // 128 KB
  u16* bu = (u16*)(ws + 1 * MB);                  // 32 MB (swizzled)
  u16* ud = (u16*)(ws + 33 * MB);                 // 32 MB
  float* carry = (float*)(ws + 65 * MB);          // 1 MB
  float* initb = (float*)(ws + 66 * MB);          // 1 MB

  prep_k<<<256, 256, 0, stream>>>(a_raw, b, c, d, af, wq, cw);
  gemm1_k<<<4096, 256, 0, stream>>>(u, wq, af, bu, ud, carry);
  scan2_k<<<16, 256, 0, stream>>>(carry, af, initb);
  gemm2_k<<<dim3(512, 2), 512, 0, stream>>>(bu, cw, ud, af, initb, y);
}

// Round 6
// 93.032 us; speedup vs baseline: 2.1536x; 2.1536x over previous
//
#include <hip/hip_runtime.h>

#define DEV __device__ __forceinline__

typedef unsigned short u16;
typedef __attribute__((ext_vector_type(8))) __bf16 bf16x8;
typedef __attribute__((ext_vector_type(4))) float f32x4;
typedef __attribute__((ext_vector_type(8))) unsigned short u16x8;
typedef __attribute__((ext_vector_type(4))) unsigned short u16x4;

// Problem constants: B=16, T=4096, Din=Dout=S=256
static constexpr int NB = 16;
static constexpr int NT = 4096;
static constexpr int NCH = 64;   // chunks per batch (L = 64)
static constexpr int LCH = 64;

DEV u16 f2bf(float f) {
  unsigned u = __builtin_bit_cast(unsigned, f);
  u += 0x7fffu + ((u >> 16) & 1u);
  return (u16)(u >> 16);
}
DEV float bf2f(u16 h) {
  unsigned u = ((unsigned)h) << 16;
  return __builtin_bit_cast(float, u);
}

DEV void gl_lds16(const void* gp, void* lp) {
  __builtin_amdgcn_global_load_lds(
      (__attribute__((address_space(1))) void*)(void*)gp,
      (__attribute__((address_space(3))) void*)lp, 16, 0, 0);
}

// ---------------- prep: a = tanh(a_raw); b,c,d -> bf16 ----------------
__global__ __launch_bounds__(256) void prep_k(const float* __restrict__ a_raw,
                                              const float* __restrict__ b,
                                              const float* __restrict__ c,
                                              const float* __restrict__ d,
                                              float* __restrict__ af,
                                              u16* __restrict__ bw,
                                              u16* __restrict__ cw,
                                              u16* __restrict__ dw) {
  int i = blockIdx.x * 256 + threadIdx.x;  // grid 256 -> i < 65536
  if (i < 256) af[i] = tanhf(a_raw[i]);
  bw[i] = f2bf(b[i]);
  cw[i] = f2bf(c[i]);
  dw[i] = f2bf(d[i]);
}

// ---------------- u fp32 -> bf16, 8 elems/thread ----------------
__global__ __launch_bounds__(256) void convu_k(const float* __restrict__ u,
                                               u16* __restrict__ ub) {
  size_t i = ((size_t)blockIdx.x * 256 + threadIdx.x) * 8;
  float4 v0 = *reinterpret_cast<const float4*>(u + i);
  float4 v1 = *reinterpret_cast<const float4*>(u + i + 4);
  u16x8 o;
  o[0] = f2bf(v0.x); o[1] = f2bf(v0.y); o[2] = f2bf(v0.z); o[3] = f2bf(v0.w);
  o[4] = f2bf(v1.x); o[5] = f2bf(v1.y); o[6] = f2bf(v1.z); o[7] = f2bf(v1.w);
  *reinterpret_cast<u16x8*>(ub + i) = o;
}

// ---------------- gemm1: Bu = u @ b^T (swizzled bf16) + per-chunk carries --------
// R1-proven shape: 256 thr / 4 waves (2x2), 128x128 tile, BK=64, gl_lds both
// operands with pre-swizzled source (rule 21). grid (2, 512): panel fastest so
// the two col-panels of the same A rows are dispatch-adjacent (L2 reuse).
// Wave tile 64x64: wave (wm,wn) covers rows wm*64..+64 = exactly one scan chunk,
// so the chunk carry carry[chunk][s] = sum_t a_s^(63-t) Bu[t][s] is computed
// in-register from the accumulators (verified R3/R4 code, ni extended to 4).
__global__ __launch_bounds__(256) void gemm1_k(const u16* __restrict__ ubf,
                                               const u16* __restrict__ bw,
                                               const float* __restrict__ af,
                                               u16* __restrict__ bu,
                                               float* __restrict__ carry) {
  __shared__ u16 As[128 * 64];
  __shared__ u16 Bs[128 * 64];
  const int tid = threadIdx.x;
  const int lane = tid & 63;
  const int wid = tid >> 6;
  const int wm = wid >> 1, wn = wid & 1;
  const int panel = blockIdx.x;           // 0/1 -> bu cols 0..127 / 128..255
  const size_t row0 = (size_t)blockIdx.y * 128;
  const int col0 = panel * 128;

  const int rstg = tid >> 3;  // 0..31
  const int c16 = tid & 7;

  const f32x4 zero = {0.f, 0.f, 0.f, 0.f};
  f32x4 acc[4][4];
#pragma unroll
  for (int i = 0; i < 4; ++i)
#pragma unroll
    for (int j = 0; j < 4; ++j) acc[i][j] = zero;

#pragma unroll
  for (int kt = 0; kt < 4; ++kt) {
    const int kb = kt * 64;
#pragma unroll
    for (int j = 0; j < 4; ++j) {
      int row = j * 32 + rstg;
      int sc = c16 ^ (row & 7);
      gl_lds16(ubf + (row0 + row) * 256 + kb + sc * 8,
               (char*)As + j * 4096 + wid * 1024);
      gl_lds16(bw + (size_t)(col0 + row) * 256 + kb + sc * 8,
               (char*)Bs + j * 4096 + wid * 1024);
    }
    __syncthreads();
#pragma unroll
    for (int kk = 0; kk < 2; ++kk) {
      const int ks = kk * 4 + (lane >> 4);
      bf16x8 afr[4], bfr[4];
#pragma unroll
      for (int mi = 0; mi < 4; ++mi) {
        int ar = wm * 64 + mi * 16 + (lane & 15);
        afr[mi] = *reinterpret_cast<const bf16x8*>(&As[ar * 64 + (ks ^ (ar & 7)) * 8]);
      }
#pragma unroll
      for (int ni = 0; ni < 4; ++ni) {
        int br = wn * 64 + ni * 16 + (lane & 15);
        bfr[ni] = *reinterpret_cast<const bf16x8*>(&Bs[br * 64 + (ks ^ (br & 7)) * 8]);
      }
#pragma unroll
      for (int mi = 0; mi < 4; ++mi)
#pragma unroll
        for (int ni = 0; ni < 4; ++ni)
          acc[mi][ni] = __builtin_amdgcn_mfma_f32_16x16x32_bf16(
              afr[mi], bfr[ni], acc[mi][ni], 0, 0, 0);
    }
    if (kt < 3) __syncthreads();
  }

  // ---- epilogue: bu written pre-swizzled (rule 21 pair with gemm2's linear gl_lds)
#pragma unroll
  for (int mi = 0; mi < 4; ++mi) {
    int rl = wm * 64 + mi * 16 + (lane >> 4) * 4;
#pragma unroll
    for (int ni = 0; ni < 4; ++ni) {
      int col = col0 + wn * 64 + ni * 16 + (lane & 15);
#pragma unroll
      for (int q = 0; q < 4; ++q) {
        size_t R = row0 + rl + q;
        bu[R * 256 + (((col >> 3) ^ ((int)R & 7)) * 8) + (col & 7)] = f2bf(acc[mi][ni][q]);
      }
    }
  }

  // ---- chunk carry (verified R3/R4): t = mi*16 + (lane>>4)*4 + q within chunk ----
  {
    const int chunk = (int)(blockIdx.y) * 2 + wm;
    const int tb = (lane >> 4) * 4;
#pragma unroll
    for (int ni = 0; ni < 4; ++ni) {
      int col = col0 + wn * 64 + ni * 16 + (lane & 15);
      float a = af[col];
      float c2 = a * a, c4 = c2 * c2, c8 = c4 * c4;
      float a12 = c8 * c4;
      float a13 = a12 * a;
      float base = (tb == 0) ? a12 : (tb == 4) ? c8 : (tb == 8) ? c4 : 1.0f;
      float p = base, s = 0.f;
#pragma unroll
      for (int mi = 3; mi >= 0; --mi) {
#pragma unroll
        for (int q = 3; q >= 0; --q) {
          s = fmaf(p, acc[mi][ni][q], s);
          if (q) p *= a;
        }
        if (mi) p *= a13;  // exponent +13: from (mi,q=0) to (mi-1,q=3)
      }
      s += __shfl_xor(s, 16, 64);
      s += __shfl_xor(s, 32, 64);
      if ((lane >> 4) == 0) carry[(size_t)chunk * 256 + col] = s;
    }
  }
}

// ---------------- scan2: exclusive scan of carries over 64 chunks ----------------
__global__ __launch_bounds__(256) void scan2_k(const float* __restrict__ carry,
                                               const float* __restrict__ af,
                                               float* __restrict__ initb) {
  int b = blockIdx.x;  // 16
  int s = threadIdx.x;
  float a = af[s];
  float aL = a;
#pragma unroll
  for (int i = 0; i < 6; ++i) aL *= aL;  // a^64
  float x = 0.f;
  for (int k = 0; k < NCH; ++k) {
    size_t idx = ((size_t)(b * NCH + k)) * 256 + s;
    float cv = carry[idx];
    initb[idx] = x;
    x = fmaf(aL, x, cv);
  }
}

// ---------------- gemm2: y = xs@c^T + u@d^T (K=512), in-LDS xs recon ------------
// grid (2, 512): by = row tile (chunk pair), bx = col half (fastest -> L2 reuse of
// the staged bu tile). 512 thr, 8 waves 2x4, wave tile 64x32.
// LDS: XS [128][256] bf16 swizzled (64KB, also reused as A-tile buffer in phase B)
//      CS [128][64] (16KB, weight tiles).
// Phase A: recon xs in LDS, 4 K-steps vs cw. Phase B: 4 K-steps ubf vs dw.
__global__ __launch_bounds__(512, 4) void gemm2_k(const u16* __restrict__ bu,
                                                  const u16* __restrict__ cw,
                                                  const u16* __restrict__ dw,
                                                  const u16* __restrict__ ubf,
                                                  const float* __restrict__ af,
                                                  const float* __restrict__ initb,
                                                  float* __restrict__ y) {
  __shared__ u16 XS[128 * 256];
  __shared__ u16 CS[128 * 64];
  const int tid = threadIdx.x;
  const int lane = tid & 63;
  const int wid = tid >> 6;
  const int wr = wid >> 2, wc = wid & 3;
  const int bx = blockIdx.y;          // rows bx*128..+128 ; chunks 2bx, 2bx+1
  const int col0 = blockIdx.x * 128;

  // stage bu tile (linear copy; data pre-swizzled in global)
  const char* src = (const char*)bu + (size_t)bx * 65536;
#pragma unroll
  for (int j = 0; j < 8; ++j)
    gl_lds16(src + j * 8192 + tid * 16, (char*)XS + j * 8192 + wid * 1024);
  // stage C step 0
#pragma unroll
  for (int r = 0; r < 2; ++r) {
    int brow = r * 64 + (tid >> 3);
    int sc = (tid & 7) ^ (brow & 7);
    gl_lds16(cw + (size_t)(col0 + brow) * 256 + 0 + sc * 8,
             (char*)CS + r * 8192 + wid * 1024);
  }
  __syncthreads();

  // ---- recon xs in place: 2 chunk halves x 256 states ----
  {
    const int hf = tid >> 8;        // 0/1
    const int s = tid & 255;
    const float a = af[s];
    float x = initb[(size_t)(bx * 2 + hf) * 256 + s];
    const int r0 = hf * 64;
    const int slot = s >> 3;
    const int off = (s & 7);
#pragma unroll 8
    for (int t = 0; t < 64; ++t) {
      int r = r0 + t;
      int bi = r * 256 + ((slot ^ (r & 7)) * 8) + off;
      x = fmaf(a, x, bf2f(XS[bi]));
      XS[bi] = f2bf(x);
    }
  }

  f32x4 acc[4][2];
  const f32x4 zero = {0.f, 0.f, 0.f, 0.f};
#pragma unroll
  for (int mi = 0; mi < 4; ++mi) { acc[mi][0] = zero; acc[mi][1] = zero; }
  __syncthreads();

  // ---- phase A: K=256 over recon'd xs vs c ----
#pragma unroll
  for (int kt = 0; kt < 4; ++kt) {
#pragma unroll
    for (int kk = 0; kk < 2; ++kk) {
      const int ksl = kk * 4 + (lane >> 4);       // local slot in CS
      const int ksg = kt * 8 + ksl;               // global slot in XS
      bf16x8 afr[4], bfr[2];
#pragma unroll
      for (int mi = 0; mi < 4; ++mi) {
        int ar = wr * 64 + mi * 16 + (lane & 15);
        afr[mi] = *reinterpret_cast<const bf16x8*>(&XS[ar * 256 + ((ksg ^ (ar & 7)) * 8)]);
      }
#pragma unroll
      for (int ni = 0; ni < 2; ++ni) {
        int nr = wc * 32 + ni * 16 + (lane & 15);
        bfr[ni] = *reinterpret_cast<const bf16x8*>(&CS[nr * 64 + ((ksl ^ (nr & 7)) * 8)]);
      }
#pragma unroll
      for (int mi = 0; mi < 4; ++mi)
#pragma unroll
        for (int ni = 0; ni < 2; ++ni)
          acc[mi][ni] = __builtin_amdgcn_mfma_f32_16x16x32_bf16(
              afr[mi], bfr[ni], acc[mi][ni], 0, 0, 0);
    }
    if (kt < 3) {
      __syncthreads();  // readers done with CS
#pragma unroll
      for (int r = 0; r < 2; ++r) {
        int brow = r * 64 + (tid >> 3);
        int sc = (tid & 7) ^ (brow & 7);
        gl_lds16(cw + (size_t)(col0 + brow) * 256 + (kt + 1) * 64 + sc * 8,
                 (char*)CS + r * 8192 + wid * 1024);
      }
      __syncthreads();  // staged (vmcnt drained)
    }
  }

  // ---- phase B: K=256 over ubf vs d. A-tiles staged into XS[0..16KB) ----
#pragma unroll
  for (int kt = 0; kt < 4; ++kt) {
    __syncthreads();  // previous-step reads of XS/CS complete
#pragma unroll
    for (int j = 0; j < 2; ++j) {
      int row = j * 64 + (tid >> 3);
      int sc = (tid & 7) ^ (row & 7);
      gl_lds16(ubf + ((size_t)bx * 128 + row) * 256 + kt * 64 + sc * 8,
               (char*)XS + j * 8192 + wid * 1024);
    }
#pragma unroll
    for (int r = 0; r < 2; ++r) {
      int brow = r * 64 + (tid >> 3);
      int sc = (tid & 7) ^ (brow & 7);
      gl_lds16(dw + (size_t)(col0 + brow) * 256 + kt * 64 + sc * 8,
               (char*)CS + r * 8192 + wid * 1024);
    }
    __syncthreads();  // staged (vmcnt drained)
#pragma unroll
    for (int kk = 0; kk < 2; ++kk) {
      const int ksl = kk * 4 + (lane >> 4);
      bf16x8 afr[4], bfr[2];
#pragma unroll
      for (int mi = 0; mi < 4; ++mi) {
        int ar = wr * 64 + mi * 16 + (lane & 15);
        afr[mi] = *reinterpret_cast<const bf16x8*>(
            (const char*)XS + ar * 128 + ((ksl ^ (ar & 7)) * 16));
      }
#pragma unroll
      for (int ni = 0; ni < 2; ++ni) {
        int nr = wc * 32 + ni * 16 + (lane & 15);
        bfr[ni] = *reinterpret_cast<const bf16x8*>(&CS[nr * 64 + ((ksl ^ (nr & 7)) * 8)]);
      }
#pragma unroll
      for (int mi = 0; mi < 4; ++mi)
#pragma unroll
        for (int ni = 0; ni < 2; ++ni)
          acc[mi][ni] = __builtin_amdgcn_mfma_f32_16x16x32_bf16(
              afr[mi], bfr[ni], acc[mi][ni], 0, 0, 0);
    }
  }

  // ---- epilogue: y fp32 ----
#pragma unroll
  for (int mi = 0; mi < 4; ++mi) {
    int rlb = wr * 64 + mi * 16 + (lane >> 4) * 4;
#pragma unroll
    for (int ni = 0; ni < 2; ++ni) {
      int col = col0 + wc * 32 + ni * 16 + (lane & 15);
#pragma unroll
      for (int q = 0; q < 4; ++q)
        y[(size_t)(bx * 128 + rlb + q) * 256 + col] = acc[mi][ni][q];
    }
  }
}

extern "C" void kernel_launch(void* const* d_in, const int* in_sizes, int n_in,
                              void* d_out, int out_size, void* d_ws, size_t ws_size,
                              hipStream_t stream) {
  const float* u = (const float*)d_in[0];
  const float* a_raw = (const float*)d_in[1];
  const float* b = (const float*)d_in[2];
  const float* c = (const float*)d_in[3];
  const float* d = (const float*)d_in[4];
  float* y = (float*)d_out;
  char* ws = (char*)d_ws;

  const size_t MB = 1u << 20;
  float* af = (float*)(ws);                       // 1 KB
  u16* bw = (u16*)(ws + 4096);                    // 128 KB
  u16* cw = (u16*)(ws + 4096 + 131072);           // 128 KB
  u16* dw = (u16*)(ws + 4096 + 2 * 131072);       // 128 KB
  u16* ubf = (u16*)(ws + 1 * MB);                 // 32 MB
  u16* bu = (u16*)(ws + 33 * MB);                 // 32 MB (swizzled)
  float* carry = (float*)(ws + 65 * MB);          // 1 MB
  float* initb = (float*)(ws + 66 * MB);          // 1 MB

  prep_k<<<256, 256, 0, stream>>>(a_raw, b, c, d, af, bw, cw, dw);
  convu_k<<<8192, 256, 0, stream>>>(u, ubf);
  gemm1_k<<<dim3(2, 512), 256, 0, stream>>>(ubf, bw, af, bu, carry);
  scan2_k<<<16, 256, 0, stream>>>(carry, af, initb);
  gemm2_k<<<dim3(2, 512), 512, 0, stream>>>(bu, cw, dw, ubf, af, initb, y);
}